// Round 1
// baseline (173.393 us; speedup 1.0000x reference)
//
#include <hip/hip_runtime.h>

#define BB 32
#define SS 512
#define DD 768

typedef float f32x4 __attribute__((ext_vector_type(4)));
typedef short bf16x8 __attribute__((ext_vector_type(8)));

// order-preserving float -> uint key (monotone under unsigned compare)
__device__ __forceinline__ unsigned fkey(float f) {
  unsigned u = __float_as_uint(f);
  return (u & 0x80000000u) ? ~u : (u | 0x80000000u);
}
__device__ __forceinline__ float fdecode(unsigned k) {
  return __uint_as_float((k & 0x80000000u) ? (k & 0x7fffffffu) : ~k);
}
// f32 -> bf16 round-to-nearest-even
__device__ __forceinline__ unsigned short cvt_bf16(float f) {
  unsigned u = __float_as_uint(f);
  u += 0x7fffu + ((u >> 16) & 1u);
  return (unsigned short)(u >> 16);
}

// ---------------- Kernel A: inv-norms + max-key init ----------------
__global__ __launch_bounds__(256) void norms_kernel(
    const float* __restrict__ emb1, const float* __restrict__ emb2,
    float* __restrict__ inv1, float* __restrict__ inv2,
    unsigned* __restrict__ rowkey, unsigned* __restrict__ colkey) {
  int wave = blockIdx.x * 4 + (threadIdx.x >> 6);  // 32768 waves total
  int lane = threadIdx.x & 63;
  int half = wave >> 14;            // 16384 rows per input
  int r = wave & 16383;
  const float* src = (half ? emb2 : emb1) + (size_t)r * DD;
  const float4* p = (const float4*)src;
  float s = 0.f;
#pragma unroll
  for (int q = 0; q < 3; ++q) {     // 192 float4 per row / 64 lanes
    float4 v = p[q * 64 + lane];
    s += v.x * v.x + v.y * v.y + v.z * v.z + v.w * v.w;
  }
#pragma unroll
  for (int m = 1; m < 64; m <<= 1) s += __shfl_xor(s, m);
  if (lane == 0) {
    float inv = 1.0f / fmaxf(sqrtf(s), 1e-8f);
    if (half == 0) { inv1[r] = inv; rowkey[r] = 0x007fffffu; }  // key(-inf)
    else           { inv2[r] = inv; colkey[r] = 0x007fffffu; }
  }
}

// ---------------- Kernel B: bf16-MFMA sim tile + masked row/col max ----------------
// tile 128x128, BK=64, 4 waves (2x2 of 64x64), XOR-swizzled LDS.
__global__ __launch_bounds__(256) void simmax_kernel(
    const float* __restrict__ emb1, const float* __restrict__ emb2,
    const int* __restrict__ mask1, const int* __restrict__ mask2,
    const float* __restrict__ inv1, const float* __restrict__ inv2,
    unsigned* __restrict__ rowkey, unsigned* __restrict__ colkey) {
  int b = blockIdx.y;
  int i0 = (blockIdx.x >> 2) << 7;
  int j0 = (blockIdx.x & 3) << 7;
  __shared__ __align__(16) unsigned short sA[128 * 64];
  __shared__ __align__(16) unsigned short sB[128 * 64];
  __shared__ float sInv1[128], sInv2[128];
  __shared__ int sM1[128], sM2[128];
  int t = threadIdx.x;
  if (t < 128) {
    sInv1[t] = inv1[b * SS + i0 + t];
    sM1[t]   = mask1[b * SS + i0 + t];
  } else {
    int u = t - 128;
    sInv2[u] = inv2[b * SS + j0 + u];
    sM2[u]   = mask2[b * SS + j0 + u];
  }
  const float* Ab = emb1 + ((size_t)b * SS + i0) * DD;
  const float* Bb = emb2 + ((size_t)b * SS + j0) * DD;
  int l = t & 63, wid = t >> 6, wr = wid >> 1, wc = wid & 1;
  f32x4 acc[4][4] = {};

  for (int k0 = 0; k0 < DD; k0 += 64) {
    __syncthreads();  // previous iteration's LDS reads done before overwrite
#pragma unroll 4
    for (int pp = 0; pp < 8; ++pp) {
      int flat = pp * 256 + t;
      int r = flat >> 4, f4 = flat & 15;        // row 0..127, float4-col 0..15
      const float4 va = *(const float4*)(Ab + (size_t)r * DD + k0 + f4 * 4);
      const float4 vb = *(const float4*)(Bb + (size_t)r * DD + k0 + f4 * 4);
      // swizzled element index: row*64 + (chunk8 ^ (row&7))*8 + within
      int el = (r << 6) + ((((f4 >> 1) ^ (r & 7)) << 3) | ((f4 & 1) << 2));
      ushort4 ua, ub;
      ua.x = cvt_bf16(va.x); ua.y = cvt_bf16(va.y); ua.z = cvt_bf16(va.z); ua.w = cvt_bf16(va.w);
      ub.x = cvt_bf16(vb.x); ub.y = cvt_bf16(vb.y); ub.z = cvt_bf16(vb.z); ub.w = cvt_bf16(vb.w);
      *(ushort4*)(&sA[el]) = ua;
      *(ushort4*)(&sB[el]) = ub;
    }
    __syncthreads();
#pragma unroll
    for (int kk = 0; kk < 2; ++kk) {
      bf16x8 af[4], bfr[4];
#pragma unroll
      for (int mi = 0; mi < 4; ++mi) {
        int r = wr * 64 + mi * 16 + (l & 15);
        int ch = (kk << 2) + (l >> 4);
        af[mi] = *(const bf16x8*)(&sA[(r << 6) + ((ch ^ (r & 7)) << 3)]);
      }
#pragma unroll
      for (int ni = 0; ni < 4; ++ni) {
        int r = wc * 64 + ni * 16 + (l & 15);
        int ch = (kk << 2) + (l >> 4);
        bfr[ni] = *(const bf16x8*)(&sB[(r << 6) + ((ch ^ (r & 7)) << 3)]);
      }
#pragma unroll
      for (int mi = 0; mi < 4; ++mi)
#pragma unroll
        for (int ni = 0; ni < 4; ++ni)
          acc[mi][ni] = __builtin_amdgcn_mfma_f32_16x16x32_bf16(af[mi], bfr[ni], acc[mi][ni], 0, 0, 0);
    }
  }

  // ---- epilogue: scale by inv-norms, mask, row/col max, atomic publish ----
  const float NEG = -__builtin_inff();
  float rmax[4][4], cmax[4];
#pragma unroll
  for (int mi = 0; mi < 4; ++mi)
#pragma unroll
    for (int rg = 0; rg < 4; ++rg) rmax[mi][rg] = NEG;
#pragma unroll
  for (int ni = 0; ni < 4; ++ni) cmax[ni] = NEG;

#pragma unroll
  for (int mi = 0; mi < 4; ++mi) {
#pragma unroll
    for (int ni = 0; ni < 4; ++ni) {
#pragma unroll
      for (int rg = 0; rg < 4; ++rg) {
        int rl = wr * 64 + mi * 16 + (l >> 4) * 4 + rg;  // C/D: row=(lane>>4)*4+reg
        int cl = wc * 64 + ni * 16 + (l & 15);           // C/D: col=lane&15
        float v = acc[mi][ni][rg] * sInv1[rl] * sInv2[cl];
        v = (sM1[rl] && sM2[cl]) ? v : NEG;
        rmax[mi][rg] = fmaxf(rmax[mi][rg], v);
        cmax[ni] = fmaxf(cmax[ni], v);
      }
    }
  }
  // row max: reduce across the 16 lanes holding the row's 16 cols (xor bits 0-3)
#pragma unroll
  for (int mi = 0; mi < 4; ++mi)
#pragma unroll
    for (int rg = 0; rg < 4; ++rg) {
      float v = rmax[mi][rg];
      v = fmaxf(v, __shfl_xor(v, 1));
      v = fmaxf(v, __shfl_xor(v, 2));
      v = fmaxf(v, __shfl_xor(v, 4));
      v = fmaxf(v, __shfl_xor(v, 8));
      rmax[mi][rg] = v;
    }
  // col max: reduce across the 4 row-groups (xor bits 4-5)
#pragma unroll
  for (int ni = 0; ni < 4; ++ni) {
    float v = cmax[ni];
    v = fmaxf(v, __shfl_xor(v, 16));
    v = fmaxf(v, __shfl_xor(v, 32));
    cmax[ni] = v;
  }
  // each lane publishes one distinct row and one distinct col of its wave's 64x64
  int selm = (l >> 2) & 3, selr = l & 3, seln = (l >> 4) & 3;
  float rv = rmax[0][0], cv = cmax[0];
#pragma unroll
  for (int mi = 0; mi < 4; ++mi)
#pragma unroll
    for (int rg = 0; rg < 4; ++rg)
      if (selm == mi && selr == rg) rv = rmax[mi][rg];
#pragma unroll
  for (int ni = 0; ni < 4; ++ni)
    if (seln == ni) cv = cmax[ni];
  int rl = selm * 16 + ((l >> 4) & 3) * 4 + selr;  // bijection over 64 rows
  int cl = seln * 16 + (l & 15);                   // bijection over 64 cols
  atomicMax(&rowkey[b * SS + i0 + wr * 64 + rl], fkey(rv));
  atomicMax(&colkey[b * SS + j0 + wc * 64 + cl], fkey(cv));
}

// ---------------- Kernel C: finalize scores ----------------
__global__ __launch_bounds__(256) void finalize_kernel(
    const int* __restrict__ mask1, const int* __restrict__ mask2,
    const unsigned* __restrict__ rowkey, const unsigned* __restrict__ colkey,
    float* __restrict__ out) {
  int b = blockIdx.x, t = threadIdx.x;
  float sum = 0.f;
  int cnt = 0;
  for (int s = t; s < SS; s += 256) {
    if (mask1[b * SS + s]) { sum += fdecode(rowkey[b * SS + s]); cnt++; }
    if (mask2[b * SS + s]) { sum += fdecode(colkey[b * SS + s]); cnt++; }
  }
#pragma unroll
  for (int m = 1; m < 64; m <<= 1) {
    sum += __shfl_xor(sum, m);
    cnt += __shfl_xor(cnt, m);
  }
  __shared__ float sS[4];
  __shared__ int sC[4];
  int w = t >> 6, lane = t & 63;
  if (lane == 0) { sS[w] = sum; sC[w] = cnt; }
  __syncthreads();
  if (t == 0) {
    float T = sS[0] + sS[1] + sS[2] + sS[3];
    int C = sC[0] + sC[1] + sC[2] + sC[3];
    out[b] = T / fmaxf((float)C, 1.0f);
  }
}

extern "C" void kernel_launch(void* const* d_in, const int* in_sizes, int n_in,
                              void* d_out, int out_size, void* d_ws, size_t ws_size,
                              hipStream_t stream) {
  const float* emb1 = (const float*)d_in[0];
  const float* emb2 = (const float*)d_in[1];
  const int* mask1 = (const int*)d_in[2];
  const int* mask2 = (const int*)d_in[3];
  float* out = (float*)d_out;

  float* inv1 = (float*)d_ws;
  float* inv2 = inv1 + BB * SS;
  unsigned* rowkey = (unsigned*)(inv2 + BB * SS);
  unsigned* colkey = rowkey + BB * SS;

  norms_kernel<<<8192, 256, 0, stream>>>(emb1, emb2, inv1, inv2, rowkey, colkey);
  simmax_kernel<<<dim3(16, BB), 256, 0, stream>>>(emb1, emb2, mask1, mask2,
                                                  inv1, inv2, rowkey, colkey);
  finalize_kernel<<<BB, 256, 0, stream>>>(mask1, mask2, rowkey, colkey, out);
}

// Round 2
// 151.194 us; speedup vs baseline: 1.1468x; 1.1468x over previous
//
#include <hip/hip_runtime.h>

#define BB 32
#define SS 512
#define DD 768
#define NROW (BB * SS)  // 16384 rows per input

typedef float f32x4 __attribute__((ext_vector_type(4)));
typedef short bf16x8 __attribute__((ext_vector_type(8)));

// order-preserving float -> uint key (monotone under unsigned compare)
__device__ __forceinline__ unsigned fkey(float f) {
  unsigned u = __float_as_uint(f);
  return (u & 0x80000000u) ? ~u : (u | 0x80000000u);
}
__device__ __forceinline__ float fdecode(unsigned k) {
  return __uint_as_float((k & 0x80000000u) ? (k & 0x7fffffffu) : ~k);
}
// f32 -> bf16 round-to-nearest-even
__device__ __forceinline__ unsigned short cvt_bf16(float f) {
  unsigned u = __float_as_uint(f);
  u += 0x7fffu + ((u >> 16) & 1u);
  return (unsigned short)(u >> 16);
}

// ---------------- Kernel A: normalize -> bf16, PRE-SWIZZLED layout ----------------
// ws layout per row: within each 64-elem block, 8-elem chunk c stored at c^(row&7).
// A linear global_load_lds copy then yields the XOR-swizzled LDS tile directly.
__global__ __launch_bounds__(256) void norm_cvt_kernel(
    const float* __restrict__ emb1, const float* __restrict__ emb2,
    unsigned short* __restrict__ wsA, unsigned short* __restrict__ wsB,
    unsigned* __restrict__ rowkey, unsigned* __restrict__ colkey) {
  int wave = blockIdx.x * 4 + (threadIdx.x >> 6);  // 32768 waves
  int lane = threadIdx.x & 63;
  int half = wave >> 14;
  int r = wave & (NROW - 1);
  const float* src = (half ? emb2 : emb1) + (size_t)r * DD;
  float4 v[3];
  float s = 0.f;
#pragma unroll
  for (int q = 0; q < 3; ++q) {
    v[q] = ((const float4*)src)[q * 64 + lane];
    s += v[q].x * v[q].x + v[q].y * v[q].y + v[q].z * v[q].z + v[q].w * v[q].w;
  }
#pragma unroll
  for (int m = 1; m < 64; m <<= 1) s += __shfl_xor(s, m);
  float inv = 1.0f / fmaxf(sqrtf(s), 1e-8f);
  unsigned short* dst = (half ? wsB : wsA) + (size_t)r * DD;
  // lane's 4 elems at e = q*256 + lane*4: chunk c=(lane>>1)&7 -> c^(r&7)
  int base = ((lane >> 4) << 6) + (((((lane >> 1) & 7) ^ (r & 7))) << 3) + ((lane & 1) << 2);
#pragma unroll
  for (int q = 0; q < 3; ++q) {
    ushort4 u;
    u.x = cvt_bf16(v[q].x * inv); u.y = cvt_bf16(v[q].y * inv);
    u.z = cvt_bf16(v[q].z * inv); u.w = cvt_bf16(v[q].w * inv);
    *(ushort4*)(dst + q * 256 + base) = u;
  }
  if (lane == 0) {
    if (half == 0) rowkey[r] = 0x007fffffu;  // key(-inf)
    else           colkey[r] = 0x007fffffu;
  }
}

// ---------------- Kernel B: bf16 MFMA sim tile + masked row/col max ----------------
// 128x128 tile, BK=64, 4 waves (2x2 of 64x64). gload_lds(16B) staging, dbuf,
// 2-phase (prefetch t+1 before compute t), 1 barrier/step. XCD-aware block decode.
__global__ __launch_bounds__(256) void simmax_kernel(
    const unsigned short* __restrict__ wsA, const unsigned short* __restrict__ wsB,
    const int* __restrict__ mask1, const int* __restrict__ mask2,
    unsigned* __restrict__ rowkey, unsigned* __restrict__ colkey) {
  int x = blockIdx.x;
  // XCD = blockIdx % 8 (round-robin): keep all 16 tiles of a batch on one XCD
  int b = (x & 7) + (((x >> 3) & 3) << 3);
  int tile = x >> 5;
  int i0 = (tile >> 2) << 7;
  int j0 = (tile & 3) << 7;
  __shared__ __align__(16) unsigned short sA[2][128 * 64];
  __shared__ __align__(16) unsigned short sB[2][128 * 64];
  __shared__ int sM1[128], sM2[128];
  int t = threadIdx.x, l = t & 63, wid = t >> 6, wr = wid >> 1, wc = wid & 1;
  if (t < 128) sM1[t] = mask1[b * SS + i0 + t];
  else sM2[t - 128] = mask2[b * SS + j0 + (t - 128)];
  const unsigned short* gA = wsA + (size_t)(b * SS + i0) * DD;
  const unsigned short* gB = wsB + (size_t)(b * SS + j0) * DD;
  int rsub = l >> 3, csub = l & 7;  // lane -> (row-in-8, 16B-chunk)

  f32x4 acc[4][4] = {};

#define STAGE(buf, k0)                                                              \
  {                                                                                 \
    _Pragma("unroll") for (int j = 0; j < 4; ++j) {                                 \
      int rowblk = (wid * 4 + j) * 8;                                               \
      const unsigned short* ga = gA + (size_t)(rowblk + rsub) * DD + (k0) + csub * 8; \
      const unsigned short* gb = gB + (size_t)(rowblk + rsub) * DD + (k0) + csub * 8; \
      __builtin_amdgcn_global_load_lds(                                             \
          (const __attribute__((address_space(1))) unsigned int*)ga,                \
          (__attribute__((address_space(3))) unsigned int*)&sA[buf][rowblk * 64],   \
          16, 0, 0);                                                                \
      __builtin_amdgcn_global_load_lds(                                             \
          (const __attribute__((address_space(1))) unsigned int*)gb,                \
          (__attribute__((address_space(3))) unsigned int*)&sB[buf][rowblk * 64],   \
          16, 0, 0);                                                                \
    }                                                                               \
  }

  STAGE(0, 0);
  __syncthreads();
  int cur = 0;
#pragma unroll 1
  for (int tk = 0; tk < 12; ++tk) {
    if (tk < 11) STAGE(cur ^ 1, (tk + 1) * 64);
#pragma unroll
    for (int kk = 0; kk < 2; ++kk) {
      bf16x8 af[4], bfr[4];
#pragma unroll
      for (int mi = 0; mi < 4; ++mi) {
        int r = wr * 64 + mi * 16 + (l & 15);
        int ch = (kk << 2) + (l >> 4);
        af[mi] = *(const bf16x8*)(&sA[cur][(r << 6) + ((ch ^ (r & 7)) << 3)]);
      }
#pragma unroll
      for (int ni = 0; ni < 4; ++ni) {
        int r = wc * 64 + ni * 16 + (l & 15);
        int ch = (kk << 2) + (l >> 4);
        bfr[ni] = *(const bf16x8*)(&sB[cur][(r << 6) + ((ch ^ (r & 7)) << 3)]);
      }
#pragma unroll
      for (int mi = 0; mi < 4; ++mi)
#pragma unroll
        for (int ni = 0; ni < 4; ++ni)
          acc[mi][ni] = __builtin_amdgcn_mfma_f32_16x16x32_bf16(af[mi], bfr[ni], acc[mi][ni], 0, 0, 0);
    }
    __syncthreads();
    cur ^= 1;
  }

  // ---- epilogue: mask, row/col max, atomic publish (data pre-normalized) ----
  const float NEG = -__builtin_inff();
  float rmax[4][4], cmax[4];
#pragma unroll
  for (int mi = 0; mi < 4; ++mi)
#pragma unroll
    for (int rg = 0; rg < 4; ++rg) rmax[mi][rg] = NEG;
#pragma unroll
  for (int ni = 0; ni < 4; ++ni) cmax[ni] = NEG;

#pragma unroll
  for (int mi = 0; mi < 4; ++mi) {
#pragma unroll
    for (int ni = 0; ni < 4; ++ni) {
#pragma unroll
      for (int rg = 0; rg < 4; ++rg) {
        int rl = wr * 64 + mi * 16 + (l >> 4) * 4 + rg;  // C/D: row=(lane>>4)*4+reg
        int cl = wc * 64 + ni * 16 + (l & 15);           // C/D: col=lane&15
        float v = acc[mi][ni][rg];
        v = (sM1[rl] && sM2[cl]) ? v : NEG;
        rmax[mi][rg] = fmaxf(rmax[mi][rg], v);
        cmax[ni] = fmaxf(cmax[ni], v);
      }
    }
  }
#pragma unroll
  for (int mi = 0; mi < 4; ++mi)
#pragma unroll
    for (int rg = 0; rg < 4; ++rg) {
      float v = rmax[mi][rg];
      v = fmaxf(v, __shfl_xor(v, 1));
      v = fmaxf(v, __shfl_xor(v, 2));
      v = fmaxf(v, __shfl_xor(v, 4));
      v = fmaxf(v, __shfl_xor(v, 8));
      rmax[mi][rg] = v;
    }
#pragma unroll
  for (int ni = 0; ni < 4; ++ni) {
    float v = cmax[ni];
    v = fmaxf(v, __shfl_xor(v, 16));
    v = fmaxf(v, __shfl_xor(v, 32));
    cmax[ni] = v;
  }
  int selm = (l >> 2) & 3, selr = l & 3, seln = (l >> 4) & 3;
  float rv = rmax[0][0], cv = cmax[0];
#pragma unroll
  for (int mi = 0; mi < 4; ++mi)
#pragma unroll
    for (int rg = 0; rg < 4; ++rg)
      if (selm == mi && selr == rg) rv = rmax[mi][rg];
#pragma unroll
  for (int ni = 0; ni < 4; ++ni)
    if (seln == ni) cv = cmax[ni];
  int rl = selm * 16 + ((l >> 4) & 3) * 4 + selr;  // bijection over 64 rows
  int cl = seln * 16 + (l & 15);                   // bijection over 64 cols
  atomicMax(&rowkey[b * SS + i0 + wr * 64 + rl], fkey(rv));
  atomicMax(&colkey[b * SS + j0 + wc * 64 + cl], fkey(cv));
}

// ---------------- Kernel C: finalize scores ----------------
__global__ __launch_bounds__(256) void finalize_kernel(
    const int* __restrict__ mask1, const int* __restrict__ mask2,
    const unsigned* __restrict__ rowkey, const unsigned* __restrict__ colkey,
    float* __restrict__ out) {
  int b = blockIdx.x, t = threadIdx.x;
  float sum = 0.f;
  int cnt = 0;
  for (int s = t; s < SS; s += 256) {
    if (mask1[b * SS + s]) { sum += fdecode(rowkey[b * SS + s]); cnt++; }
    if (mask2[b * SS + s]) { sum += fdecode(colkey[b * SS + s]); cnt++; }
  }
#pragma unroll
  for (int m = 1; m < 64; m <<= 1) {
    sum += __shfl_xor(sum, m);
    cnt += __shfl_xor(cnt, m);
  }
  __shared__ float sS[4];
  __shared__ int sC[4];
  int w = t >> 6, lane = t & 63;
  if (lane == 0) { sS[w] = sum; sC[w] = cnt; }
  __syncthreads();
  if (t == 0) {
    float T = sS[0] + sS[1] + sS[2] + sS[3];
    int C = sC[0] + sC[1] + sC[2] + sC[3];
    out[b] = T / fmaxf((float)C, 1.0f);
  }
}

extern "C" void kernel_launch(void* const* d_in, const int* in_sizes, int n_in,
                              void* d_out, int out_size, void* d_ws, size_t ws_size,
                              hipStream_t stream) {
  const float* emb1 = (const float*)d_in[0];
  const float* emb2 = (const float*)d_in[1];
  const int* mask1 = (const int*)d_in[2];
  const int* mask2 = (const int*)d_in[3];
  float* out = (float*)d_out;

  unsigned short* wsA = (unsigned short*)d_ws;                   // 25.2 MB
  unsigned short* wsB = wsA + (size_t)NROW * DD;                 // 25.2 MB
  unsigned* rowkey = (unsigned*)(wsB + (size_t)NROW * DD);       // 64 KB
  unsigned* colkey = rowkey + NROW;                              // 64 KB

  norm_cvt_kernel<<<8192, 256, 0, stream>>>(emb1, emb2, wsA, wsB, rowkey, colkey);
  simmax_kernel<<<512, 256, 0, stream>>>(wsA, wsB, mask1, mask2, rowkey, colkey);
  finalize_kernel<<<BB, 256, 0, stream>>>(mask1, mask2, rowkey, colkey, out);
}